// Round 3
// baseline (287.812 us; speedup 1.0000x reference)
//
#include <hip/hip_runtime.h>
#include <hip/hip_cooperative_groups.h>
#include <math.h>

namespace cg = cooperative_groups;

constexpr int Bn = 64;
constexpr int Dn = 1024;
constexpr float LOG2E = 1.4426950408889634f;
constexpr float LN2   = 0.6931471805599453f;

__device__ __forceinline__ float exp2_fast(float v) {
#if defined(__has_builtin)
#if __has_builtin(__builtin_amdgcn_exp2f)
  return __builtin_amdgcn_exp2f(v);
#else
  return exp2f(v);
#endif
#else
  return exp2f(v);
#endif
}

// ---------------------------------------------------------------------------
// Shared-memory layouts for the two phase types, overlaid in a union so the
// fused kernel pays max(23.0, 37.5) = 37.5 KB -> 4 blocks/CU (150/160 KB).
// ---------------------------------------------------------------------------
struct SortSmem {
  float  xs_[Dn];
  float2 prs_[Dn];                       // {x*log2e, -Bsum*log2e}
  int    bkt_[Dn];
  float4 desc_[128];
  int    cnt[64], base_[64], off_[64];
  float  Ssum[64], cN[64], cS[64];
  float  redM[4][64], redE[4][64], redD[4][64];
};
struct LayerSmem {
  float s[8][Dn + 4];
  float red[8][8][16];                   // [bl][nl][kc]
  float r2[8][8][2];
};
union Smem {
  SortSmem srt;
  LayerSmem lyr;
};

// ---------------------------------------------------------------------------
// Phase 1: fused bucket-sort + analytic Bsum + softsort for (b, rc) = blk.
// Sort: bucket via sigmoid(1.702x) ~ Phi(x) -> near-uniform 64 buckets;
// Bsum = x*(Nlo-Nhi)+(Shi-Slo)+sum_{same bucket}|x-x_k|  (exact under any
// intra-bucket permutation).  Group-of-8 descriptors hold exact (a,c) of the
// group's min-x/max-x elements (concave endpoint bound) for the vote-skip.
// Also zeroes d_out (block 0) for the tail layer's atomicAdds.
// ---------------------------------------------------------------------------
__device__ __forceinline__ void sortsoft_phase(
    Smem* smp, int blk, int tid, const float* __restrict__ x,
    float* __restrict__ xs_out, float* __restrict__ out) {
  SortSmem& sm = smp->srt;
  int b  = blk >> 4;
  int rc = blk & 15;

  if (tid < 64) { sm.cnt[tid] = 0; sm.off_[tid] = 0; sm.Ssum[tid] = 0.f; }
  if (blk == 0 && tid < 128) out[tid] = 0.f;
  __syncthreads();

  // ---- bucket count ----
  float4 v4 = *(const float4*)(x + b * Dn + tid * 4);
  float xv[4] = {v4.x, v4.y, v4.z, v4.w};
  int bk[4];
#pragma unroll
  for (int u = 0; u < 4; ++u) {
    float z = exp2_fast(-2.455532f * xv[u]);   // 2^{-1.702 x log2e}, monotone
    float p = 1.f / (1.f + z);                 // ~Phi(x): near-uniform buckets
    int t = (int)(p * 64.f);
    bk[u] = t < 0 ? 0 : (t > 63 ? 63 : t);
    atomicAdd(&sm.cnt[bk[u]], 1);
    atomicAdd(&sm.Ssum[bk[u]], xv[u]);
  }
  __syncthreads();

  // ---- dual prefix scan (wave 0) ----
  if (tid < 64) {
    int c = sm.cnt[tid]; int si = c;
    float fs = sm.Ssum[tid]; float ss = fs;
#pragma unroll
    for (int d = 1; d < 64; d <<= 1) {
      int oi = __shfl_up(si, d, 64);
      float os = __shfl_up(ss, d, 64);
      if (tid >= d) { si += oi; ss += os; }
    }
    sm.base_[tid] = si - c;                       // Nlo (exclusive)
    float Stot = __shfl(ss, 63, 64);
    float Slo = ss - fs;                          // exclusive sum prefix
    sm.cN[tid] = (float)(2 * (si - c) + c - Dn);  // Nlo - Nhi
    sm.cS[tid] = Stot - 2.f * Slo - fs;           // Shi - Slo
  }
  __syncthreads();

  // ---- scatter ----
#pragma unroll
  for (int u = 0; u < 4; ++u) {
    int pos = sm.base_[bk[u]] + atomicAdd(&sm.off_[bk[u]], 1);
    sm.xs_[pos] = xv[u];
    sm.bkt_[pos] = bk[u];
  }
  __syncthreads();

  // ---- exact Bsum per position ----
#pragma unroll
  for (int r = 0; r < 4; ++r) {
    int p = r * 256 + tid;
    float xp = sm.xs_[p];
    int q = sm.bkt_[p];
    int lo = sm.base_[q], hi = lo + sm.cnt[q];
    float local = 0.f;
    for (int k = lo; k < hi; ++k) local += fabsf(xp - sm.xs_[k]);
    float Bs = fmaf(xp, sm.cN[q], sm.cS[q]) + local;
    sm.prs_[p] = make_float2(xp * LOG2E, -Bs * LOG2E);
  }
  __syncthreads();

  // ---- group descriptors (one group of 8 per thread, 128 groups) ----
  if (tid < 128) {
    int base = tid * 8;
    float xlo = sm.xs_[base], xhi = xlo;
    int ilo = base, ihi = base;
#pragma unroll
    for (int k = 1; k < 8; ++k) {
      float xx = sm.xs_[base + k];
      if (xx < xlo) { xlo = xx; ilo = base + k; }
      if (xx > xhi) { xhi = xx; ihi = base + k; }
    }
    float2 plo = sm.prs_[ilo], phi = sm.prs_[ihi];
    sm.desc_[tid] = make_float4(plo.x, plo.y, phi.x, phi.y);
  }
  __syncthreads();

  // ---- softsort: lane = row; 4 waves own interleaved groups g = 4q+w ----
  int w = tid >> 6, lane = tid & 63;
  int i = rc * 64 + lane;
  float sc = (float)(Dn - 1 - 2 * i);             // exact in fp32
  float gm[32];
  float m = -3.4e38f;
#pragma unroll 8
  for (int q = 0; q < 32; ++q) {
    float4 d = sm.desc_[q * 4 + w];               // wave-uniform broadcast
    float t0 = fmaf(sc, d.x, d.y);                // T at group's min-x element
    float t1 = fmaf(sc, d.z, d.w);                // T at group's max-x element
    float g = fmaxf(t0, t1);
    gm[q] = g;
    m = fmaxf(m, g);
  }
  sm.redM[w][lane] = m;
  __syncthreads();
  float M = fmaxf(fmaxf(sm.redM[0][lane], sm.redM[1][lane]),
                  fmaxf(sm.redM[2][lane], sm.redM[3][lane]));
  float thresh = M - 32.f;

  float se = 0.f, sd = 0.f;
#pragma unroll 4
  for (int q = 0; q < 32; ++q) {
    if (__any(gm[q] > thresh)) {
      int base = (q * 4 + w) * 8;
#pragma unroll
      for (int u = 0; u < 8; ++u) {
        float2 v = sm.prs_[base + u];             // wave-uniform broadcast
        float e = exp2_fast(fmaf(sc, v.x, v.y - M));
        se += e;
        sd = fmaf(e, v.x, sd);
      }
    }
  }
  sm.redE[w][lane] = se;
  sm.redD[w][lane] = sd;
  __syncthreads();
  if (tid < 64) {
    float SE = (sm.redE[0][lane] + sm.redE[1][lane]) +
               (sm.redE[2][lane] + sm.redE[3][lane]);
    float SD = (sm.redD[0][lane] + sm.redD[1][lane]) +
               (sm.redD[2][lane] + sm.redD[3][lane]);
    xs_out[b * Dn + rc * 64 + lane] = SD / SE * LN2;
  }
}

// ---------------------------------------------------------------------------
// Phase 2/3: h = leaky(in @ W^T + bias).  Block = 8 batches x 8 cols; thread
// tile = 1 batch x 4 cols x K/16.  XCD-aware swizzle: xcd = blk&7 owns a
// contiguous 16-chunk nc range (512 KB of W resident in that XCD's L2).
// tail fuses layer 3 into atomicAdds on d_out (zeroed in phase 1).
// ---------------------------------------------------------------------------
__device__ __forceinline__ void layer_phase(
    Smem* smp, int blk, int tid, const float* __restrict__ in,
    const float* __restrict__ W, const float* __restrict__ bias,
    float* __restrict__ out, bool tail, const float* __restrict__ W3,
    const float* __restrict__ b3, float* __restrict__ out2) {
  float (*s)[Dn + 4] = smp->lyr.s;
  float (*red)[8][16] = smp->lyr.red;
  float (*r2)[8][2] = smp->lyr.r2;
  int xcd = blk & 7;
  int idx = blk >> 3;                    // 0..127
  int nc = xcd * 16 + (idx & 15);        // col chunk 0..127
  int bc = idx >> 4;                     // batch chunk 0..7
  const float* src = in + bc * 8 * Dn;
#pragma unroll
  for (int u = 0; u < 8; ++u) {
    int idx2 = (u * 256 + tid) << 2;
    *(float4*)&s[idx2 >> 10][idx2 & 1023] = *(const float4*)(src + idx2);
  }
  __syncthreads();

  int bl = tid & 7;                      // local batch
  int nq = (tid >> 3) & 1;               // col quad 0..1
  int kc = tid >> 4;                     // k chunk 0..15 (64 elems)
  int n0 = nc * 8 + nq * 4;
  const float* a  = &s[bl][kc * 64];
  const float* w0 = W + (size_t)(n0 + 0) * Dn + kc * 64;
  const float* w1 = W + (size_t)(n0 + 1) * Dn + kc * 64;
  const float* w2 = W + (size_t)(n0 + 2) * Dn + kc * 64;
  const float* w3 = W + (size_t)(n0 + 3) * Dn + kc * 64;
  float a0 = 0.f, a1 = 0.f, a2 = 0.f, a3 = 0.f;
#pragma unroll 4
  for (int kq = 0; kq < 16; ++kq) {
    float4 av = *(const float4*)(a + kq * 4);
    float4 b0 = *(const float4*)(w0 + kq * 4);
    float4 b1 = *(const float4*)(w1 + kq * 4);
    float4 b2 = *(const float4*)(w2 + kq * 4);
    float4 b3v = *(const float4*)(w3 + kq * 4);
    a0 = fmaf(av.x, b0.x, fmaf(av.y, b0.y, fmaf(av.z, b0.z, fmaf(av.w, b0.w, a0))));
    a1 = fmaf(av.x, b1.x, fmaf(av.y, b1.y, fmaf(av.z, b1.z, fmaf(av.w, b1.w, a1))));
    a2 = fmaf(av.x, b2.x, fmaf(av.y, b2.y, fmaf(av.z, b2.z, fmaf(av.w, b2.w, a2))));
    a3 = fmaf(av.x, b3v.x, fmaf(av.y, b3v.y, fmaf(av.z, b3v.z, fmaf(av.w, b3v.w, a3))));
  }
  red[bl][nq * 4 + 0][kc] = a0;
  red[bl][nq * 4 + 1][kc] = a1;
  red[bl][nq * 4 + 2][kc] = a2;
  red[bl][nq * 4 + 3][kc] = a3;
  __syncthreads();

  if (!tail) {
    if (tid < 64) {
      int bl2 = tid >> 3, nl2 = tid & 7;
      int n2 = nc * 8 + nl2;
      float hs = 0.f;
#pragma unroll
      for (int q = 0; q < 16; ++q) hs += red[bl2][nl2][q];
      float h = hs + bias[n2];
      h = h >= 0.f ? h : 0.01f * h;
      out[(bc * 8 + bl2) * Dn + n2] = h;
    }
  } else {
    if (tid < 64) {
      int bl2 = tid >> 3, nl2 = tid & 7;
      int n2 = nc * 8 + nl2;
      float hs = 0.f;
#pragma unroll
      for (int q = 0; q < 16; ++q) hs += red[bl2][nl2][q];
      float h = hs + bias[n2];
      h = h >= 0.f ? h : 0.01f * h;
      r2[bl2][nl2][0] = h * W3[n2];
      r2[bl2][nl2][1] = h * W3[Dn + n2];
    }
    __syncthreads();
    if (tid < 16) {
      int bl2 = tid >> 1, o = tid & 1;
      float t = 0.f;
#pragma unroll
      for (int q = 0; q < 8; ++q) t += r2[bl2][q][o];
      if (nc == 0) t += b3[o];
      atomicAdd(out2 + (bc * 8 + bl2) * 2 + o, t);
    }
  }
}

// ---------------------------------------------------------------------------
// Fused single-dispatch pipeline: sortsoft -> grid.sync -> L1 -> grid.sync ->
// L2+L3.  grid = 1024 blocks of 256; union LDS 37.5 KB -> 4 blocks/CU ->
// exactly co-resident (runtime-verified by the cooperative launch).
// ---------------------------------------------------------------------------
__global__ __launch_bounds__(256, 4) void fused_all(
    const float* __restrict__ x,
    const float* __restrict__ W1, const float* __restrict__ b1,
    const float* __restrict__ W2, const float* __restrict__ b2,
    const float* __restrict__ W3, const float* __restrict__ b3,
    float* __restrict__ xs, float* __restrict__ h1,
    float* __restrict__ out) {
  __shared__ Smem sm;
  cg::grid_group grid = cg::this_grid();
  int blk = blockIdx.x;
  int tid = threadIdx.x;

  sortsoft_phase(&sm, blk, tid, x, xs, out);
  grid.sync();
  layer_phase(&sm, blk, tid, xs, W1, b1, h1, false, nullptr, nullptr, nullptr);
  grid.sync();
  layer_phase(&sm, blk, tid, h1, W2, b2, nullptr, true, W3, b3, out);
}

// --------------------- fallback: 3 separate dispatches ----------------------
__global__ __launch_bounds__(256) void k_sortsoft(
    const float* __restrict__ x, float* __restrict__ xs_out,
    float* __restrict__ out) {
  __shared__ Smem sm;
  sortsoft_phase(&sm, blockIdx.x, threadIdx.x, x, xs_out, out);
}

template <bool TAIL>
__global__ __launch_bounds__(256) void layer_kernel(
    const float* __restrict__ in, const float* __restrict__ W,
    const float* __restrict__ bias, float* __restrict__ out,
    const float* __restrict__ W3, const float* __restrict__ b3,
    float* __restrict__ out2) {
  __shared__ Smem sm;
  layer_phase(&sm, blockIdx.x, threadIdx.x, in, W, bias, out, TAIL, W3, b3,
              out2);
}

extern "C" void kernel_launch(void* const* d_in, const int* in_sizes, int n_in,
                              void* d_out, int out_size, void* d_ws, size_t ws_size,
                              hipStream_t stream) {
  const float* x  = (const float*)d_in[0];
  const float* W1 = (const float*)d_in[1];
  const float* b1 = (const float*)d_in[2];
  const float* W2 = (const float*)d_in[3];
  const float* b2 = (const float*)d_in[4];
  const float* W3 = (const float*)d_in[5];
  const float* b3 = (const float*)d_in[6];
  float* out = (float*)d_out;
  float* ws = (float*)d_ws;

  float* xs = ws;                // 64*1024 floats = 256 KB
  float* h1 = xs + Bn * Dn;      // 256 KB

  void* args[] = {(void*)&x,  (void*)&W1, (void*)&b1, (void*)&W2, (void*)&b2,
                  (void*)&W3, (void*)&b3, (void*)&xs, (void*)&h1, (void*)&out};
  hipError_t e = hipLaunchCooperativeKernel(
      (const void*)fused_all, dim3(Bn * 16), dim3(256), args, 0, stream);
  if (e != hipSuccess) {
    // Cooperative launch unavailable (e.g. under this capture mode): fall
    // back to the equivalent 3-dispatch pipeline.
    k_sortsoft<<<Bn * 16, 256, 0, stream>>>(x, xs, out);
    layer_kernel<false><<<1024, 256, 0, stream>>>(xs, W1, b1, h1,
                                                  nullptr, nullptr, nullptr);
    layer_kernel<true><<<1024, 256, 0, stream>>>(h1, W2, b2, nullptr,
                                                 W3, b3, out);
  }
}

// Round 4
// 125.244 us; speedup vs baseline: 2.2980x; 2.2980x over previous
//
#include <hip/hip_runtime.h>
#include <math.h>

constexpr int Bn = 64;
constexpr int Dn = 1024;
constexpr float LOG2E = 1.4426950408889634f;
constexpr float LN2   = 0.6931471805599453f;

__device__ __forceinline__ float exp2_fast(float v) {
#if defined(__has_builtin)
#if __has_builtin(__builtin_amdgcn_exp2f)
  return __builtin_amdgcn_exp2f(v);
#else
  return exp2f(v);
#endif
#else
  return exp2f(v);
#endif
}

// ---------------------------------------------------------------------------
// K_SORTSOFT v2: one block per batch b (64 blocks x 1024 threads).
// The bucket sort runs ONCE per b (was duplicated x16 across rc-blocks), and
// thread == output row, so the row softmax needs no cross-wave reduction.
// Numerics are bit-identical to the previous (passing) version: the survivor
// sums use 4 sub-accumulators combined (s0+s1)+(s2+s3) in the old wave order,
// the __any vote spans the same 64 consecutive rows, and the row max is pure
// fmax (associative-exact).
// Sort: bucket via sigmoid(1.702x) ~ Phi(x) -> near-uniform 64 buckets;
// Bsum = x*(Nlo-Nhi)+(Shi-Slo)+sum_{same bucket}|x-x_k|  (exact under any
// intra-bucket permutation).  Group-of-8 descriptors hold exact (a,c) of the
// group's min-x/max-x elements (concave endpoint bound) for the vote-skip.
// Zeroes d_out (block 0) for the tail layer's atomicAdds.
// ---------------------------------------------------------------------------
__global__ __launch_bounds__(1024) void k_sortsoft(
    const float* __restrict__ x, float* __restrict__ xs_out,
    float* __restrict__ out) {
  __shared__ float  xs_[Dn];
  __shared__ float2 prs_[Dn];            // {x*log2e, -Bsum*log2e}
  __shared__ int    bkt_[Dn];
  __shared__ float4 desc_[128];
  __shared__ int   cnt[64], base_[64], off_[64];
  __shared__ float Ssum[64], cN[64], cS[64];

  int b   = blockIdx.x;
  int tid = threadIdx.x;

  if (tid < 64) { cnt[tid] = 0; off_[tid] = 0; Ssum[tid] = 0.f; }
  if (b == 0 && tid < 128) out[tid] = 0.f;
  __syncthreads();

  // ---- bucket count (1 element per thread) ----
  float xv = x[b * Dn + tid];
  int bk;
  {
    float z = exp2_fast(-2.455532f * xv);      // 2^{-1.702 x log2e}, monotone
    float p = 1.f / (1.f + z);                 // ~Phi(x): near-uniform buckets
    int t = (int)(p * 64.f);
    bk = t < 0 ? 0 : (t > 63 ? 63 : t);
    atomicAdd(&cnt[bk], 1);
    atomicAdd(&Ssum[bk], xv);
  }
  __syncthreads();

  // ---- dual prefix scan (wave 0) ----
  if (tid < 64) {
    int c = cnt[tid]; int si = c;
    float fs = Ssum[tid]; float ss = fs;
#pragma unroll
    for (int d = 1; d < 64; d <<= 1) {
      int oi = __shfl_up(si, d, 64);
      float os = __shfl_up(ss, d, 64);
      if (tid >= d) { si += oi; ss += os; }
    }
    base_[tid] = si - c;                       // Nlo (exclusive)
    float Stot = __shfl(ss, 63, 64);
    float Slo = ss - fs;                       // exclusive sum prefix
    cN[tid] = (float)(2 * (si - c) + c - Dn);  // Nlo - Nhi
    cS[tid] = Stot - 2.f * Slo - fs;           // Shi - Slo
  }
  __syncthreads();

  // ---- scatter ----
  {
    int pos = base_[bk] + atomicAdd(&off_[bk], 1);
    xs_[pos] = xv;
    bkt_[pos] = bk;
  }
  __syncthreads();

  // ---- exact Bsum per position (1 per thread) ----
  {
    float xp = xs_[tid];
    int q = bkt_[tid];
    int lo = base_[q], hi = lo + cnt[q];
    float local = 0.f;
    for (int k = lo; k < hi; ++k) local += fabsf(xp - xs_[k]);
    float Bs = fmaf(xp, cN[q], cS[q]) + local;
    prs_[tid] = make_float2(xp * LOG2E, -Bs * LOG2E);
  }
  __syncthreads();

  // ---- group descriptors (one group of 8 per thread, 128 groups) ----
  if (tid < 128) {
    int base = tid * 8;
    float xlo = xs_[base], xhi = xlo;
    int ilo = base, ihi = base;
#pragma unroll
    for (int k = 1; k < 8; ++k) {
      float xx = xs_[base + k];
      if (xx < xlo) { xlo = xx; ilo = base + k; }
      if (xx > xhi) { xhi = xx; ihi = base + k; }
    }
    float2 plo = prs_[ilo], phi = prs_[ihi];
    desc_[tid] = make_float4(plo.x, plo.y, phi.x, phi.y);
  }
  __syncthreads();

  // ---- softsort: thread == row; full row per thread, no reductions ----
  float sc = (float)(Dn - 1 - 2 * tid);        // exact in fp32

  // pass 1: row max M over all 128 group endpoint bounds (pure fmax)
  float M = -3.4e38f;
#pragma unroll 8
  for (int g = 0; g < 128; ++g) {
    float4 d = desc_[g];                       // wave-uniform broadcast
    float t0 = fmaf(sc, d.x, d.y);             // T at group's min-x element
    float t1 = fmaf(sc, d.z, d.w);             // T at group's max-x element
    M = fmaxf(M, fmaxf(t0, t1));
  }
  float thresh = M - 32.f;

  // pass 2: survivor sums, 4 sub-accumulators in the legacy wave order
  float se[4] = {0.f, 0.f, 0.f, 0.f};
  float sd[4] = {0.f, 0.f, 0.f, 0.f};
#pragma unroll 2
  for (int q = 0; q < 32; ++q) {
#pragma unroll
    for (int w = 0; w < 4; ++w) {
      float4 d = desc_[q * 4 + w];
      float gv = fmaxf(fmaf(sc, d.x, d.y), fmaf(sc, d.z, d.w));
      if (__any(gv > thresh)) {                // vote over 64 consecutive rows
        int base = (q * 4 + w) * 8;
#pragma unroll
        for (int u = 0; u < 8; ++u) {
          float2 v = prs_[base + u];           // wave-uniform broadcast
          float e = exp2_fast(fmaf(sc, v.x, v.y - M));
          se[w] += e;
          sd[w] = fmaf(e, v.x, sd[w]);
        }
      }
    }
  }
  float SE = (se[0] + se[1]) + (se[2] + se[3]);
  float SD = (sd[0] + sd[1]) + (sd[2] + sd[3]);
  xs_out[b * Dn + tid] = SD / SE * LN2;
}

// ---------------------------------------------------------------------------
// K3/K4: h = leaky(in @ W^T + bias).  Block = 8 batches x 8 cols; thread
// tile = 1 batch x 4 cols x K/16.  grid = 1024 blocks.
// XCD-aware swizzle: xcd = blk&7 owns a contiguous 16-chunk nc range
// (512 KB of W, resident in that XCD's 4 MiB L2 across its 8 bc-blocks)
// -> ~8x less L3 W traffic.  Heuristic only; correctness placement-free.
// TAIL fuses layer 3 into atomicAdds on d_out (zeroed by k_sortsoft).
// ---------------------------------------------------------------------------
template <bool TAIL>
__global__ __launch_bounds__(256) void layer_kernel(
    const float* __restrict__ in, const float* __restrict__ W,
    const float* __restrict__ bias, float* __restrict__ out,
    const float* __restrict__ W3, const float* __restrict__ b3,
    float* __restrict__ out2) {
  __shared__ float s[8][Dn + 4];
  __shared__ float red[8][8][16];          // [bl][nl][kc]
  __shared__ float r2[8][8][2];
  int xcd = blockIdx.x & 7;
  int idx = blockIdx.x >> 3;               // 0..127
  int nc = xcd * 16 + (idx & 15);          // col chunk 0..127
  int bc = idx >> 4;                       // batch chunk 0..7
  int tid = threadIdx.x;
  const float* src = in + bc * 8 * Dn;
#pragma unroll
  for (int u = 0; u < 8; ++u) {
    int idx2 = (u * 256 + tid) << 2;
    *(float4*)&s[idx2 >> 10][idx2 & 1023] = *(const float4*)(src + idx2);
  }
  __syncthreads();

  int bl = tid & 7;                        // local batch
  int nq = (tid >> 3) & 1;                 // col quad 0..1
  int kc = tid >> 4;                       // k chunk 0..15 (64 elems)
  int n0 = nc * 8 + nq * 4;
  const float* a  = &s[bl][kc * 64];
  const float* w0 = W + (size_t)(n0 + 0) * Dn + kc * 64;
  const float* w1 = W + (size_t)(n0 + 1) * Dn + kc * 64;
  const float* w2 = W + (size_t)(n0 + 2) * Dn + kc * 64;
  const float* w3 = W + (size_t)(n0 + 3) * Dn + kc * 64;
  float a0 = 0.f, a1 = 0.f, a2 = 0.f, a3 = 0.f;
#pragma unroll 4
  for (int kq = 0; kq < 16; ++kq) {
    float4 av = *(const float4*)(a + kq * 4);
    float4 b0 = *(const float4*)(w0 + kq * 4);
    float4 b1 = *(const float4*)(w1 + kq * 4);
    float4 b2 = *(const float4*)(w2 + kq * 4);
    float4 b3v = *(const float4*)(w3 + kq * 4);
    a0 = fmaf(av.x, b0.x, fmaf(av.y, b0.y, fmaf(av.z, b0.z, fmaf(av.w, b0.w, a0))));
    a1 = fmaf(av.x, b1.x, fmaf(av.y, b1.y, fmaf(av.z, b1.z, fmaf(av.w, b1.w, a1))));
    a2 = fmaf(av.x, b2.x, fmaf(av.y, b2.y, fmaf(av.z, b2.z, fmaf(av.w, b2.w, a2))));
    a3 = fmaf(av.x, b3v.x, fmaf(av.y, b3v.y, fmaf(av.z, b3v.z, fmaf(av.w, b3v.w, a3))));
  }
  red[bl][nq * 4 + 0][kc] = a0;
  red[bl][nq * 4 + 1][kc] = a1;
  red[bl][nq * 4 + 2][kc] = a2;
  red[bl][nq * 4 + 3][kc] = a3;
  __syncthreads();

  if (!TAIL) {
    if (tid < 64) {
      int bl2 = tid >> 3, nl2 = tid & 7;
      int n2 = nc * 8 + nl2;
      float hs = 0.f;
#pragma unroll
      for (int q = 0; q < 16; ++q) hs += red[bl2][nl2][q];
      float h = hs + bias[n2];
      h = h >= 0.f ? h : 0.01f * h;
      out[(bc * 8 + bl2) * Dn + n2] = h;
    }
  } else {
    if (tid < 64) {
      int bl2 = tid >> 3, nl2 = tid & 7;
      int n2 = nc * 8 + nl2;
      float hs = 0.f;
#pragma unroll
      for (int q = 0; q < 16; ++q) hs += red[bl2][nl2][q];
      float h = hs + bias[n2];
      h = h >= 0.f ? h : 0.01f * h;
      r2[bl2][nl2][0] = h * W3[n2];
      r2[bl2][nl2][1] = h * W3[Dn + n2];
    }
    __syncthreads();
    if (tid < 16) {
      int bl2 = tid >> 1, o = tid & 1;
      float t = 0.f;
#pragma unroll
      for (int q = 0; q < 8; ++q) t += r2[bl2][q][o];
      if (nc == 0) t += b3[o];
      atomicAdd(out2 + (bc * 8 + bl2) * 2 + o, t);
    }
  }
}

extern "C" void kernel_launch(void* const* d_in, const int* in_sizes, int n_in,
                              void* d_out, int out_size, void* d_ws, size_t ws_size,
                              hipStream_t stream) {
  const float* x  = (const float*)d_in[0];
  const float* W1 = (const float*)d_in[1];
  const float* b1 = (const float*)d_in[2];
  const float* W2 = (const float*)d_in[3];
  const float* b2 = (const float*)d_in[4];
  const float* W3 = (const float*)d_in[5];
  const float* b3 = (const float*)d_in[6];
  float* out = (float*)d_out;
  float* ws = (float*)d_ws;

  float* xs = ws;                // 64*1024 floats = 256 KB
  float* h1 = xs + Bn * Dn;      // 256 KB

  k_sortsoft<<<Bn, 1024, 0, stream>>>(x, xs, out);
  layer_kernel<false><<<1024, 256, 0, stream>>>(xs, W1, b1, h1,
                                                nullptr, nullptr, nullptr);
  layer_kernel<true><<<1024, 256, 0, stream>>>(h1, W2, b2, nullptr,
                                               W3, b3, out);
}

// Round 5
// 104.407 us; speedup vs baseline: 2.7566x; 1.1996x over previous
//
#include <hip/hip_runtime.h>
#include <math.h>

constexpr int Bn = 64;
constexpr int Dn = 1024;
constexpr float LOG2E = 1.4426950408889634f;
constexpr float LN2   = 0.6931471805599453f;

__device__ __forceinline__ float exp2_fast(float v) {
#if defined(__has_builtin)
#if __has_builtin(__builtin_amdgcn_exp2f)
  return __builtin_amdgcn_exp2f(v);
#else
  return exp2f(v);
#endif
#else
  return exp2f(v);
#endif
}

// ---------------------------------------------------------------------------
// K_SORTSOFT (round-2 version, verbatim — measured best config).
// grid = 64 b x 16 rc = 1024 blocks of 256.  Each block re-derives its b's
// bucket sort in LDS (duplicated x16; measured neutral vs separate kernel,
// and 64x1024 one-sort variant was +15us from lost parallelism).
// ---------------------------------------------------------------------------
__global__ __launch_bounds__(256) void k_sortsoft(
    const float* __restrict__ x, float* __restrict__ xs_out,
    float* __restrict__ out) {
  __shared__ float  xs_[Dn];
  __shared__ float2 prs_[Dn];            // {x*log2e, -Bsum*log2e}
  __shared__ int    bkt_[Dn];
  __shared__ float4 desc_[128];
  __shared__ int   cnt[64], base_[64], off_[64];
  __shared__ float Ssum[64], cN[64], cS[64];
  __shared__ float redM[4][64], redE[4][64], redD[4][64];

  int b   = blockIdx.x >> 4;
  int rc  = blockIdx.x & 15;
  int tid = threadIdx.x;

  if (tid < 64) { cnt[tid] = 0; off_[tid] = 0; Ssum[tid] = 0.f; }
  if (blockIdx.x == 0 && tid < 128) out[tid] = 0.f;
  __syncthreads();

  // ---- bucket count ----
  float4 v4 = *(const float4*)(x + b * Dn + tid * 4);
  float xv[4] = {v4.x, v4.y, v4.z, v4.w};
  int bk[4];
#pragma unroll
  for (int u = 0; u < 4; ++u) {
    float z = exp2_fast(-2.455532f * xv[u]);   // 2^{-1.702 x log2e}, monotone
    float p = 1.f / (1.f + z);                 // ~Phi(x): near-uniform buckets
    int t = (int)(p * 64.f);
    bk[u] = t < 0 ? 0 : (t > 63 ? 63 : t);
    atomicAdd(&cnt[bk[u]], 1);
    atomicAdd(&Ssum[bk[u]], xv[u]);
  }
  __syncthreads();

  // ---- dual prefix scan (wave 0) ----
  if (tid < 64) {
    int c = cnt[tid]; int si = c;
    float fs = Ssum[tid]; float ss = fs;
#pragma unroll
    for (int d = 1; d < 64; d <<= 1) {
      int oi = __shfl_up(si, d, 64);
      float os = __shfl_up(ss, d, 64);
      if (tid >= d) { si += oi; ss += os; }
    }
    base_[tid] = si - c;                       // Nlo (exclusive)
    float Stot = __shfl(ss, 63, 64);
    float Slo = ss - fs;                       // exclusive sum prefix
    cN[tid] = (float)(2 * (si - c) + c - Dn);  // Nlo - Nhi
    cS[tid] = Stot - 2.f * Slo - fs;           // Shi - Slo
  }
  __syncthreads();

  // ---- scatter ----
#pragma unroll
  for (int u = 0; u < 4; ++u) {
    int pos = base_[bk[u]] + atomicAdd(&off_[bk[u]], 1);
    xs_[pos] = xv[u];
    bkt_[pos] = bk[u];
  }
  __syncthreads();

  // ---- exact Bsum per position ----
#pragma unroll
  for (int r = 0; r < 4; ++r) {
    int p = r * 256 + tid;
    float xp = xs_[p];
    int q = bkt_[p];
    int lo = base_[q], hi = lo + cnt[q];
    float local = 0.f;
    for (int k = lo; k < hi; ++k) local += fabsf(xp - xs_[k]);
    float Bs = fmaf(xp, cN[q], cS[q]) + local;
    prs_[p] = make_float2(xp * LOG2E, -Bs * LOG2E);
  }
  __syncthreads();

  // ---- group descriptors (one group of 8 per thread, 128 groups) ----
  if (tid < 128) {
    int base = tid * 8;
    float xlo = xs_[base], xhi = xlo;
    int ilo = base, ihi = base;
#pragma unroll
    for (int k = 1; k < 8; ++k) {
      float xx = xs_[base + k];
      if (xx < xlo) { xlo = xx; ilo = base + k; }
      if (xx > xhi) { xhi = xx; ihi = base + k; }
    }
    float2 plo = prs_[ilo], phi = prs_[ihi];
    desc_[tid] = make_float4(plo.x, plo.y, phi.x, phi.y);
  }
  __syncthreads();

  // ---- softsort: lane = row; 4 waves own interleaved groups g = 4q+w ----
  int w = tid >> 6, lane = tid & 63;
  int i = rc * 64 + lane;
  float sc = (float)(Dn - 1 - 2 * i);          // exact in fp32
  float gm[32];
  float m = -3.4e38f;
#pragma unroll 8
  for (int q = 0; q < 32; ++q) {
    float4 d = desc_[q * 4 + w];               // wave-uniform broadcast
    float t0 = fmaf(sc, d.x, d.y);             // T at group's min-x element
    float t1 = fmaf(sc, d.z, d.w);             // T at group's max-x element
    float g = fmaxf(t0, t1);
    gm[q] = g;
    m = fmaxf(m, g);
  }
  redM[w][lane] = m;
  __syncthreads();
  float M = fmaxf(fmaxf(redM[0][lane], redM[1][lane]),
                  fmaxf(redM[2][lane], redM[3][lane]));
  float thresh = M - 32.f;

  float se = 0.f, sd = 0.f;
#pragma unroll 4
  for (int q = 0; q < 32; ++q) {
    if (__any(gm[q] > thresh)) {
      int base = (q * 4 + w) * 8;
#pragma unroll
      for (int u = 0; u < 8; ++u) {
        float2 v = prs_[base + u];             // wave-uniform broadcast
        float e = exp2_fast(fmaf(sc, v.x, v.y - M));
        se += e;
        sd = fmaf(e, v.x, sd);
      }
    }
  }
  redE[w][lane] = se;
  redD[w][lane] = sd;
  __syncthreads();
  if (tid < 64) {
    float SE = (redE[0][lane] + redE[1][lane]) + (redE[2][lane] + redE[3][lane]);
    float SD = (redD[0][lane] + redD[1][lane]) + (redD[2][lane] + redD[3][lane]);
    xs_out[b * Dn + rc * 64 + lane] = SD / SE * LN2;
  }
}

// ---------------------------------------------------------------------------
// Layer kernel v2: h = leaky(in @ W^T + bias).  Block = 8 batches x 8 cols.
// Thread = (col c = tid&7, k-chunk kc = tid>>3 of 32 floats); batch is now a
// REGISTER tile acc[8], so each W element is loaded by exactly ONE thread:
// global W loads drop 64 -> 8 dwordx4 per thread (old design duplicated W x8
// across the bl-in-thread-index mapping).  The in-tile lives in LDS with a
// float4-group XOR swizzle (g ^= (g>>3)&7) making the kc-strided (128 B)
// reads conflict-free.  Per-wave shfl_xor tree reduces the 8 kc-chunks of a
// wave; red2[4][8][9] (1.1 KB) replaces the old 8 KB red array -> LDS total
// 34.4 KB keeps 4 blocks/CU.
// XCD-aware swizzle unchanged: xcd = blk&7 owns a contiguous nc range.
// TAIL fuses layer 3 into atomicAdds on d_out (zeroed by k_sortsoft).
// ---------------------------------------------------------------------------
template <bool TAIL>
__global__ __launch_bounds__(256) void layer_kernel(
    const float* __restrict__ in, const float* __restrict__ W,
    const float* __restrict__ bias, float* __restrict__ out,
    const float* __restrict__ W3, const float* __restrict__ b3,
    float* __restrict__ out2) {
  __shared__ float s[8 * Dn];              // 32 KB, float4-group XOR-swizzled
  __shared__ float red2[4][8][9];          // [wave][bl][c] (+pad col)
  __shared__ float r2[8][8][2];
  int xcd = blockIdx.x & 7;
  int idx = blockIdx.x >> 3;               // 0..127
  int nc = xcd * 16 + (idx & 15);          // col chunk 0..127
  int bc = idx >> 4;                       // batch chunk 0..7
  int tid = threadIdx.x;
  const float* src = in + bc * 8 * Dn;
  // stage in -> LDS; float4-group g of row r stored at g ^ ((g>>3)&7)
#pragma unroll
  for (int u = 0; u < 8; ++u) {
    int gl = u * 256 + tid;                // linear float4 index 0..2047
    int r = gl >> 8, g = gl & 255;
    int gs = g ^ ((g >> 3) & 7);
    *(float4*)&s[r * Dn + gs * 4] = *(const float4*)(src + gl * 4);
  }
  __syncthreads();

  int c  = tid & 7;                        // col 0..7
  int kc = tid >> 3;                       // k-chunk 0..31 (32 floats)
  int w  = tid >> 6, lane = tid & 63;
  const float* wp = W + (size_t)(nc * 8 + c) * Dn + kc * 32;
  float acc[8] = {0.f, 0.f, 0.f, 0.f, 0.f, 0.f, 0.f, 0.f};
#pragma unroll
  for (int kq = 0; kq < 8; ++kq) {
    float4 wv = *(const float4*)(wp + kq * 4);
    int gs = kc * 8 + (kq ^ (kc & 7));     // == g ^ ((g>>3)&7), g = kc*8+kq
    const float* sp = s + gs * 4;
#pragma unroll
    for (int bl = 0; bl < 8; ++bl) {
      float4 av = *(const float4*)(sp + bl * Dn);
      acc[bl] = fmaf(av.x, wv.x, fmaf(av.y, wv.y,
                fmaf(av.z, wv.z, fmaf(av.w, wv.w, acc[bl]))));
    }
  }
  // reduce the wave's 8 kc-chunks (lane>>3 axis) via shfl_xor tree
#pragma unroll
  for (int bl = 0; bl < 8; ++bl) {
    float v = acc[bl];
    v += __shfl_xor(v, 8, 64);
    v += __shfl_xor(v, 16, 64);
    v += __shfl_xor(v, 32, 64);
    acc[bl] = v;
  }
  if (lane < 8) {
#pragma unroll
    for (int bl = 0; bl < 8; ++bl) red2[w][bl][lane] = acc[bl];
  }
  __syncthreads();

  if (!TAIL) {
    if (tid < 64) {
      int bl2 = tid >> 3, nl2 = tid & 7;
      int n2 = nc * 8 + nl2;
      float hs = (red2[0][bl2][nl2] + red2[1][bl2][nl2]) +
                 (red2[2][bl2][nl2] + red2[3][bl2][nl2]);
      float h = hs + bias[n2];
      h = h >= 0.f ? h : 0.01f * h;
      out[(bc * 8 + bl2) * Dn + n2] = h;
    }
  } else {
    if (tid < 64) {
      int bl2 = tid >> 3, nl2 = tid & 7;
      int n2 = nc * 8 + nl2;
      float hs = (red2[0][bl2][nl2] + red2[1][bl2][nl2]) +
                 (red2[2][bl2][nl2] + red2[3][bl2][nl2]);
      float h = hs + bias[n2];
      h = h >= 0.f ? h : 0.01f * h;
      r2[bl2][nl2][0] = h * W3[n2];
      r2[bl2][nl2][1] = h * W3[Dn + n2];
    }
    __syncthreads();
    if (tid < 16) {
      int bl2 = tid >> 1, o = tid & 1;
      float t = 0.f;
#pragma unroll
      for (int q = 0; q < 8; ++q) t += r2[bl2][q][o];
      if (nc == 0) t += b3[o];
      atomicAdd(out2 + (bc * 8 + bl2) * 2 + o, t);
    }
  }
}

extern "C" void kernel_launch(void* const* d_in, const int* in_sizes, int n_in,
                              void* d_out, int out_size, void* d_ws, size_t ws_size,
                              hipStream_t stream) {
  const float* x  = (const float*)d_in[0];
  const float* W1 = (const float*)d_in[1];
  const float* b1 = (const float*)d_in[2];
  const float* W2 = (const float*)d_in[3];
  const float* b2 = (const float*)d_in[4];
  const float* W3 = (const float*)d_in[5];
  const float* b3 = (const float*)d_in[6];
  float* out = (float*)d_out;
  float* ws = (float*)d_ws;

  float* xs = ws;                // 64*1024 floats = 256 KB
  float* h1 = xs + Bn * Dn;      // 256 KB

  k_sortsoft<<<Bn * 16, 256, 0, stream>>>(x, xs, out);
  layer_kernel<false><<<1024, 256, 0, stream>>>(xs, W1, b1, h1,
                                                nullptr, nullptr, nullptr);
  layer_kernel<true><<<1024, 256, 0, stream>>>(h1, W2, b2, nullptr,
                                               W3, b3, out);
}

// Round 6
// 101.878 us; speedup vs baseline: 2.8251x; 1.0248x over previous
//
#include <hip/hip_runtime.h>
#include <math.h>

constexpr int Bn = 64;
constexpr int Dn = 1024;
constexpr float LOG2E = 1.4426950408889634f;
constexpr float LN2   = 0.6931471805599453f;

__device__ __forceinline__ float exp2_fast(float v) {
#if defined(__has_builtin)
#if __has_builtin(__builtin_amdgcn_exp2f)
  return __builtin_amdgcn_exp2f(v);
#else
  return exp2f(v);
#endif
#else
  return exp2f(v);
#endif
}

// ---------------------------------------------------------------------------
// K_SORTSOFT (round-2 version, verbatim — measured best config).
// grid = 64 b x 16 rc = 1024 blocks of 256.  Each block re-derives its b's
// bucket sort in LDS (duplicated x16; measured neutral vs separate kernel,
// and the 64x1024 one-sort variant was +15us from lost parallelism).
// ---------------------------------------------------------------------------
__global__ __launch_bounds__(256) void k_sortsoft(
    const float* __restrict__ x, float* __restrict__ xs_out,
    float* __restrict__ out) {
  __shared__ float  xs_[Dn];
  __shared__ float2 prs_[Dn];            // {x*log2e, -Bsum*log2e}
  __shared__ int    bkt_[Dn];
  __shared__ float4 desc_[128];
  __shared__ int   cnt[64], base_[64], off_[64];
  __shared__ float Ssum[64], cN[64], cS[64];
  __shared__ float redM[4][64], redE[4][64], redD[4][64];

  int b   = blockIdx.x >> 4;
  int rc  = blockIdx.x & 15;
  int tid = threadIdx.x;

  if (tid < 64) { cnt[tid] = 0; off_[tid] = 0; Ssum[tid] = 0.f; }
  if (blockIdx.x == 0 && tid < 128) out[tid] = 0.f;
  __syncthreads();

  // ---- bucket count ----
  float4 v4 = *(const float4*)(x + b * Dn + tid * 4);
  float xv[4] = {v4.x, v4.y, v4.z, v4.w};
  int bk[4];
#pragma unroll
  for (int u = 0; u < 4; ++u) {
    float z = exp2_fast(-2.455532f * xv[u]);   // 2^{-1.702 x log2e}, monotone
    float p = 1.f / (1.f + z);                 // ~Phi(x): near-uniform buckets
    int t = (int)(p * 64.f);
    bk[u] = t < 0 ? 0 : (t > 63 ? 63 : t);
    atomicAdd(&cnt[bk[u]], 1);
    atomicAdd(&Ssum[bk[u]], xv[u]);
  }
  __syncthreads();

  // ---- dual prefix scan (wave 0) ----
  if (tid < 64) {
    int c = cnt[tid]; int si = c;
    float fs = Ssum[tid]; float ss = fs;
#pragma unroll
    for (int d = 1; d < 64; d <<= 1) {
      int oi = __shfl_up(si, d, 64);
      float os = __shfl_up(ss, d, 64);
      if (tid >= d) { si += oi; ss += os; }
    }
    base_[tid] = si - c;                       // Nlo (exclusive)
    float Stot = __shfl(ss, 63, 64);
    float Slo = ss - fs;                       // exclusive sum prefix
    cN[tid] = (float)(2 * (si - c) + c - Dn);  // Nlo - Nhi
    cS[tid] = Stot - 2.f * Slo - fs;           // Shi - Slo
  }
  __syncthreads();

  // ---- scatter ----
#pragma unroll
  for (int u = 0; u < 4; ++u) {
    int pos = base_[bk[u]] + atomicAdd(&off_[bk[u]], 1);
    xs_[pos] = xv[u];
    bkt_[pos] = bk[u];
  }
  __syncthreads();

  // ---- exact Bsum per position ----
#pragma unroll
  for (int r = 0; r < 4; ++r) {
    int p = r * 256 + tid;
    float xp = xs_[p];
    int q = bkt_[p];
    int lo = base_[q], hi = lo + cnt[q];
    float local = 0.f;
    for (int k = lo; k < hi; ++k) local += fabsf(xp - xs_[k]);
    float Bs = fmaf(xp, cN[q], cS[q]) + local;
    prs_[p] = make_float2(xp * LOG2E, -Bs * LOG2E);
  }
  __syncthreads();

  // ---- group descriptors (one group of 8 per thread, 128 groups) ----
  if (tid < 128) {
    int base = tid * 8;
    float xlo = xs_[base], xhi = xlo;
    int ilo = base, ihi = base;
#pragma unroll
    for (int k = 1; k < 8; ++k) {
      float xx = xs_[base + k];
      if (xx < xlo) { xlo = xx; ilo = base + k; }
      if (xx > xhi) { xhi = xx; ihi = base + k; }
    }
    float2 plo = prs_[ilo], phi = prs_[ihi];
    desc_[tid] = make_float4(plo.x, plo.y, phi.x, phi.y);
  }
  __syncthreads();

  // ---- softsort: lane = row; 4 waves own interleaved groups g = 4q+w ----
  int w = tid >> 6, lane = tid & 63;
  int i = rc * 64 + lane;
  float sc = (float)(Dn - 1 - 2 * i);          // exact in fp32
  float gm[32];
  float m = -3.4e38f;
#pragma unroll 8
  for (int q = 0; q < 32; ++q) {
    float4 d = desc_[q * 4 + w];               // wave-uniform broadcast
    float t0 = fmaf(sc, d.x, d.y);             // T at group's min-x element
    float t1 = fmaf(sc, d.z, d.w);             // T at group's max-x element
    float g = fmaxf(t0, t1);
    gm[q] = g;
    m = fmaxf(m, g);
  }
  redM[w][lane] = m;
  __syncthreads();
  float M = fmaxf(fmaxf(redM[0][lane], redM[1][lane]),
                  fmaxf(redM[2][lane], redM[3][lane]));
  float thresh = M - 32.f;

  float se = 0.f, sd = 0.f;
#pragma unroll 4
  for (int q = 0; q < 32; ++q) {
    if (__any(gm[q] > thresh)) {
      int base = (q * 4 + w) * 8;
#pragma unroll
      for (int u = 0; u < 8; ++u) {
        float2 v = prs_[base + u];             // wave-uniform broadcast
        float e = exp2_fast(fmaf(sc, v.x, v.y - M));
        se += e;
        sd = fmaf(e, v.x, sd);
      }
    }
  }
  redE[w][lane] = se;
  redD[w][lane] = sd;
  __syncthreads();
  if (tid < 64) {
    float SE = (redE[0][lane] + redE[1][lane]) + (redE[2][lane] + redE[3][lane]);
    float SD = (redD[0][lane] + redD[1][lane]) + (redD[2][lane] + redD[3][lane]);
    xs_out[b * Dn + rc * 64 + lane] = SD / SE * LN2;
  }
}

// ---------------------------------------------------------------------------
// Layer kernel v3: h = leaky(in @ W^T + bias).  Block = 8 batches x 8 cols.
// Wave = column-PAIR (c4 = tid>>6), lane = k-chunk of 16 floats.  Each LDS
// av read now feeds 2 columns (8 FMA / 16 B -> 2 B/FMA, half of v2's 4),
// cutting the layer's LDS-BW floor 3.4 -> 1.7 us/CU.  Each W element still
// loaded exactly once per block (8 b128/thread).  k-reduction is wave-local:
// 4-level routed butterfly (17 shfl, all-static indices) + 2 xor-adds lands
// output (bl = lane>>1, cl = lane&1) on lanes 0..15 -- the 8 KB red array
// and its LDS round-trip are gone.  LDS granule XOR swizzle g^((g>>3)&7)
// keeps both the staging writes and the 64 B-stride reads conflict-free.
// XCD-aware swizzle unchanged.  TAIL fuses layer 3 into atomicAdds on d_out.
// ---------------------------------------------------------------------------
template <bool TAIL>
__global__ __launch_bounds__(256) void layer_kernel(
    const float* __restrict__ in, const float* __restrict__ W,
    const float* __restrict__ bias, float* __restrict__ out,
    const float* __restrict__ W3, const float* __restrict__ b3,
    float* __restrict__ out2) {
  __shared__ float s[8 * Dn];              // 32 KB, float4-granule XOR swizzle
  __shared__ float r2[8][8][2];
  int xcd = blockIdx.x & 7;
  int idx = blockIdx.x >> 3;               // 0..127
  int nc = xcd * 16 + (idx & 15);          // col chunk 0..127
  int bc = idx >> 4;                       // batch chunk 0..7
  int tid = threadIdx.x;
  const float* src = in + bc * 8 * Dn;
  // stage in -> LDS; float4-granule g of row r stored at g ^ ((g>>3)&7)
#pragma unroll
  for (int u = 0; u < 8; ++u) {
    int gl = u * 256 + tid;                // linear float4 index 0..2047
    int r = gl >> 8, g = gl & 255;
    int gs = g ^ ((g >> 3) & 7);
    *(float4*)&s[r * Dn + gs * 4] = *(const float4*)(src + gl * 4);
  }
  __syncthreads();

  int c4   = tid >> 6;                     // wave = column pair 0..3
  int kc   = tid & 63;                     // k-chunk of 16 floats
  int lane = tid & 63;
  int n0 = nc * 8 + c4 * 2;
  const float* w0 = W + (size_t)(n0 + 0) * Dn + kc * 16;
  const float* w1 = W + (size_t)(n0 + 1) * Dn + kc * 16;
  float acc0[8] = {0.f, 0.f, 0.f, 0.f, 0.f, 0.f, 0.f, 0.f};
  float acc1[8] = {0.f, 0.f, 0.f, 0.f, 0.f, 0.f, 0.f, 0.f};
#pragma unroll
  for (int j = 0; j < 4; ++j) {
    float4 wv0 = *(const float4*)(w0 + j * 4);
    float4 wv1 = *(const float4*)(w1 + j * 4);
    int g = kc * 4 + j;
    int gs = g ^ ((g >> 3) & 7);
    const float* sp = s + gs * 4;
#pragma unroll
    for (int bl = 0; bl < 8; ++bl) {
      float4 av = *(const float4*)(sp + bl * Dn);
      acc0[bl] = fmaf(av.x, wv0.x, fmaf(av.y, wv0.y,
                 fmaf(av.z, wv0.z, fmaf(av.w, wv0.w, acc0[bl]))));
      acc1[bl] = fmaf(av.x, wv1.x, fmaf(av.y, wv1.y,
                 fmaf(av.z, wv1.z, fmaf(av.w, wv1.w, acc1[bl]))));
    }
  }

  // ---- wave-local k-reduction: routed butterfly over lane bits 0..3 ----
  // v[i], i = bl*2 + cl.  After 4 levels lane L owns index (L&15) summed
  // over its 16-lane subgroup; 2 more xor-adds finish the 64-lane sum.
  float v[16];
#pragma unroll
  for (int bl = 0; bl < 8; ++bl) { v[2 * bl] = acc0[bl]; v[2 * bl + 1] = acc1[bl]; }
#pragma unroll
  for (int bit = 0; bit < 4; ++bit) {
    int d = 1 << bit;
    bool hi = (lane & d) != 0;
#pragma unroll
    for (int i = 0; i < (8 >> bit); ++i) {
      float keep = hi ? v[2 * i + 1] : v[2 * i];
      float send = hi ? v[2 * i] : v[2 * i + 1];
      v[i] = keep + __shfl_xor(send, d, 64);
    }
  }
  float t = v[0];
  t += __shfl_xor(t, 16, 64);
  t += __shfl_xor(t, 32, 64);

  if (lane < 16) {
    int bl2 = lane >> 1, cl = lane & 1;
    int n2 = n0 + cl;
    float h = t + bias[n2];
    h = h >= 0.f ? h : 0.01f * h;
    if (!TAIL) {
      out[(bc * 8 + bl2) * Dn + n2] = h;
    } else {
      r2[bl2][c4 * 2 + cl][0] = h * W3[n2];
      r2[bl2][c4 * 2 + cl][1] = h * W3[Dn + n2];
    }
  }
  if (TAIL) {
    __syncthreads();
    if (tid < 16) {
      int bl2 = tid >> 1, o = tid & 1;
      float tt = 0.f;
#pragma unroll
      for (int q = 0; q < 8; ++q) tt += r2[bl2][q][o];
      if (nc == 0) tt += b3[o];
      atomicAdd(out2 + (bc * 8 + bl2) * 2 + o, tt);
    }
  }
}

extern "C" void kernel_launch(void* const* d_in, const int* in_sizes, int n_in,
                              void* d_out, int out_size, void* d_ws, size_t ws_size,
                              hipStream_t stream) {
  const float* x  = (const float*)d_in[0];
  const float* W1 = (const float*)d_in[1];
  const float* b1 = (const float*)d_in[2];
  const float* W2 = (const float*)d_in[3];
  const float* b2 = (const float*)d_in[4];
  const float* W3 = (const float*)d_in[5];
  const float* b3 = (const float*)d_in[6];
  float* out = (float*)d_out;
  float* ws = (float*)d_ws;

  float* xs = ws;                // 64*1024 floats = 256 KB
  float* h1 = xs + Bn * Dn;      // 256 KB

  k_sortsoft<<<Bn * 16, 256, 0, stream>>>(x, xs, out);
  layer_kernel<false><<<1024, 256, 0, stream>>>(xs, W1, b1, h1,
                                                nullptr, nullptr, nullptr);
  layer_kernel<true><<<1024, 256, 0, stream>>>(h1, W2, b2, nullptr,
                                               W3, b3, out);
}